// Round 1
// baseline (45.832 us; speedup 1.0000x reference)
//
#include <hip/hip_runtime.h>
#include <math.h>

#define CIN   8
#define COUT  8
#define HH    16
#define NN    400
#define MM    400
#define BB    16
#define KK    64

#define THREADS 512
#define NG      8   // inside-nodes processed per group (one per wave)

// LDS layout (floats unless noted):
//  W1T[32][65]   = 2080
//  W2T[256][65]  = 16640
//  W3T[16][65]   = 1040
//  lzx/lzy/lbw   = 3*400
//  kvs[NG*64]    = 512
//  ln (int)      = 400
//  wcnt/woff/cnt = 17 ints
#define SMEM_FLOATS (32*65 + 256*65 + 16*65 + 3*400 + NG*64)
#define SMEM_INTS   (400 + 8 + 8 + 1)
#define SMEM_BYTES  ((SMEM_FLOATS + SMEM_INTS) * 4)

__global__ __launch_bounds__(THREADS) void quadconv_kernel(
    const float* __restrict__ f,      // (B, CIN, NN)
    const float* __restrict__ W1,     // (K, H, 2)
    const float* __restrict__ W2,     // (K, H, H)
    const float* __restrict__ W3,     // (K, 1, H)
    const float* __restrict__ locs,   // (MM, 2)
    const float* __restrict__ nodes,  // (NN, 2)
    const float* __restrict__ wq,     // (NN,)
    float* __restrict__ out)          // (B, COUT, MM)
{
    extern __shared__ float smem[];
    float* W1T = smem;                 // [jf*65 + k], jf = j*2+d
    float* W2T = W1T + 32*65;          // [(o*16+j)*65 + k]
    float* W3T = W2T + 256*65;         // [o*65 + k]
    float* lzx = W3T + 16*65;
    float* lzy = lzx + NN;
    float* lbw = lzy + NN;
    float* kvs = lbw + NN;             // [NG*64]
    int*   ln   = (int*)(kvs + NG*64);
    int*   wcnt = ln + NN;
    int*   woff = wcnt + 8;
    int*   pcnt = woff + 8;

    const int t    = threadIdx.x;
    const int m    = blockIdx.x;
    const int lane = t & 63;
    const int w    = t >> 6;

    // ---- stage weights into LDS, transposed (lane index k innermost) ----
    for (int g = t; g < KK*HH*HH; g += THREADS) {   // W2: 16384
        int k = g >> 8, jf = g & 255;
        W2T[jf*65 + k] = W2[g];
    }
    for (int g = t; g < KK*HH*2; g += THREADS) {    // W1: 2048
        int k = g >> 5, jf = g & 31;
        W1T[jf*65 + k] = W1[g];
    }
    for (int g = t; g < KK*HH; g += THREADS) {      // W3: 1024
        int k = g >> 4, o = g & 15;
        W3T[o*65 + k] = W3[g];
    }

    // ---- phase A: find nodes inside the bump support, compact (deterministic) ----
    const float yx = locs[2*m], yy = locs[2*m + 1];
    float zx = 0.f, zy = 0.f, bw = 0.f;
    bool inside = false;
    if (t < NN) {
        float xx = nodes[2*t], xy = nodes[2*t + 1];
        zx = yx - xx; zy = yy - xy;
        float s = zx*zx + zy*zy;
        float a = s*s;                      // ||z||^4
        if (a < (1.0f/625.0f)) {
            inside = true;
            bw = expf(1.0f - 1.0f/(1.0f - 625.0f*a)) * wq[t];
        }
    }
    unsigned long long mask = __ballot(inside);
    int before = __popcll(mask & ((1ull << lane) - 1ull));
    if (lane == 0) wcnt[w] = __popcll(mask);
    __syncthreads();
    if (t == 0) {
        int off = 0;
        for (int i = 0; i < 8; ++i) { woff[i] = off; off += wcnt[i]; }
        *pcnt = off;
    }
    __syncthreads();
    if (inside) {
        int p = woff[w] + before;
        ln[p] = t; lzx[p] = zx; lzy[p] = zy; lbw[p] = bw;
    }
    __syncthreads();
    const int cnt = *pcnt;   // >= 1 (n == m gives z = 0, bump = 1)

    // ---- main loop: waves compute MLPs (lane = k), 128 threads accumulate ----
    float acc = 0.f;
    const int b = t >> 3, o = t & 7;   // valid for t < 128
    const int ngroups = (cnt + NG - 1) / NG;
    for (int g = 0; g < ngroups; ++g) {
        int slot = g*NG + w;
        float kv = 0.f;
        if (slot < cnt) {
            float szx = lzx[slot], szy = lzy[slot];
            float h1[HH];
            #pragma unroll
            for (int j = 0; j < HH; ++j)
                h1[j] = sinf(W1T[(2*j)*65 + lane]*szx + W1T[(2*j+1)*65 + lane]*szy);
            #pragma unroll
            for (int oo = 0; oo < HH; ++oo) {
                float d = 0.f;
                #pragma unroll
                for (int j = 0; j < HH; ++j)
                    d += W2T[(oo*16 + j)*65 + lane] * h1[j];
                kv += W3T[oo*65 + lane] * sinf(d);
            }
            kv *= lbw[slot];   // fold bump * quad-weight into kernel value
        }
        kvs[w*64 + lane] = kv;
        __syncthreads();
        if (t < BB*COUT) {
            int lim = min(NG, cnt - g*NG);
            const float* fb = f + b*(CIN*NN);
            for (int s = 0; s < lim; ++s) {
                int n = ln[g*NG + s];
                const float* kvrow = kvs + s*64 + o*8;
                float sum = 0.f;
                #pragma unroll
                for (int i = 0; i < CIN; ++i)
                    sum += kvrow[i] * fb[i*NN + n];
                acc += sum;
            }
        }
        __syncthreads();
    }

    if (t < BB*COUT)
        out[b*(COUT*MM) + o*MM + m] = acc;
}

extern "C" void kernel_launch(void* const* d_in, const int* in_sizes, int n_in,
                              void* d_out, int out_size, void* d_ws, size_t ws_size,
                              hipStream_t stream) {
    const float* f     = (const float*)d_in[0];
    const float* W1    = (const float*)d_in[1];
    const float* W2    = (const float*)d_in[2];
    const float* W3    = (const float*)d_in[3];
    const float* locs  = (const float*)d_in[4];
    const float* nodes = (const float*)d_in[5];
    const float* wq    = (const float*)d_in[6];
    float* out = (float*)d_out;

    quadconv_kernel<<<dim3(MM), dim3(THREADS), SMEM_BYTES, stream>>>(
        f, W1, W2, W3, locs, nodes, wq, out);
}